// Round 12
// baseline (65.231 us; speedup 1.0000x reference)
//
#include <hip/hip_runtime.h>

#define D 128
#define MAXR 96     // max rows per slot-bin (rows = 2*matches; λ=8.2 matches)

// ---------------- fallback (round-1) kernel ----------------
__global__ __launch_bounds__(256) void transe_time_kernel(
    const int* __restrict__ idx, const float* __restrict__ ent,
    const float* __restrict__ rel, const float* __restrict__ tt,
    float* __restrict__ out, int B)
{
    const int b = blockIdx.x;
    if (b >= B) return;
    const int tid = threadIdx.x;
    const int e4  = tid & 31;
    const int g   = tid >> 5;

    __shared__ float sh_h[D];
    __shared__ float sh_t[D];
    __shared__ float ph[8][D];
    __shared__ float pt[8][D];
    __shared__ float wred[8];

    const int hi = idx[b * 5 + 0];
    const int ri = idx[b * 5 + 1];
    const int ti = idx[b * 5 + 2];
    const int si = idx[b * 5 + 3];
    const int ei = idx[b * 5 + 4];

    if (tid < D) {
        sh_h[tid] = ent[(size_t)hi * D + tid];
        sh_t[tid] = ent[(size_t)ti * D + tid];
    }
    __syncthreads();

    const float4* __restrict__ Ts = (const float4*)(tt + (size_t)si * D * D);
    const float4* __restrict__ Te = (const float4*)(tt + (size_t)ei * D * D);

    float4 hacc = make_float4(0.f, 0.f, 0.f, 0.f);
    float4 tacc = make_float4(0.f, 0.f, 0.f, 0.f);

    #pragma unroll 4
    for (int d0 = 0; d0 < D; d0 += 8) {
        const int d = d0 + g;
        const float4 a = Ts[d * 32 + e4];
        const float4 c = Te[d * 32 + e4];
        const float hd = sh_h[d];
        const float td = sh_t[d];
        const float mx = a.x + c.x;
        const float my = a.y + c.y;
        const float mz = a.z + c.z;
        const float mw = a.w + c.w;
        hacc.x += hd * mx; hacc.y += hd * my; hacc.z += hd * mz; hacc.w += hd * mw;
        tacc.x += td * mx; tacc.y += td * my; tacc.z += td * mz; tacc.w += td * mw;
    }

    ((float4*)ph[g])[e4] = hacc;
    ((float4*)pt[g])[e4] = tacc;
    __syncthreads();

    float h2 = 0.f, t2 = 0.f;
    if (tid < D) {
        #pragma unroll
        for (int k = 0; k < 8; ++k) { h2 += ph[k][tid]; t2 += pt[k][tid]; }
    }
    float nh = h2 * h2;
    float nt = t2 * t2;
    #pragma unroll
    for (int off = 32; off; off >>= 1) {
        nh += __shfl_down(nh, off, 64);
        nt += __shfl_down(nt, off, 64);
    }
    const int wv = tid >> 6;
    if ((tid & 63) == 0) { wred[wv * 2] = nh; wred[wv * 2 + 1] = nt; }
    __syncthreads();
    const float NH = wred[0] + wred[2] + wred[4] + wred[6];
    const float NT2 = wred[1] + wred[3] + wred[5] + wred[7];
    const float rnh = 1.0f / fmaxf(sqrtf(NH), 1e-12f);
    const float rnt = 1.0f / fmaxf(sqrtf(NT2), 1e-12f);

    float v = 0.f;
    if (tid < D) {
        const float rr = rel[(size_t)ri * D + tid];
        v = fabsf(h2 * rnh + rr - t2 * rnt + 1e-6f);
    }
    #pragma unroll
    for (int off = 32; off; off >>= 1) v += __shfl_down(v, off, 64);
    __syncthreads();
    if ((tid & 63) == 0) wred[wv] = v;
    __syncthreads();
    if (tid == 0) out[b] = wred[0] + wred[1] + wred[2] + wred[3];
}

// ---------------- 2-kernel pipeline: scan-matvec -> score ----------------

__device__ __forceinline__ void fma4(float4& a, float s, const float4& v) {
    a.x += s * v.x; a.y += s * v.y; a.z += s * v.z; a.w += s * v.w;
}

// NG = number of live 8-row groups (wave-uniform).
template<int NG>
__device__ __forceinline__ void compute_store(
    const float* __restrict__ Tc, const float (*__restrict__ Esh)[D + 4],
    const int2* __restrict__ rows_chunk, float* __restrict__ P,
    const int col0, const int rh, const int my_rows)
{
    float4 acc[NG];
    #pragma unroll
    for (int k = 0; k < NG; ++k) acc[k] = make_float4(0.f, 0.f, 0.f, 0.f);

    #pragma unroll 2
    for (int d4 = 0; d4 < D; d4 += 4) {
        const float* tp = Tc + (size_t)d4 * D;
        const float4 t0 = *(const float4*)(tp);
        const float4 t1 = *(const float4*)(tp + D);
        const float4 t2 = *(const float4*)(tp + 2 * D);
        const float4 t3 = *(const float4*)(tp + 3 * D);
        #pragma unroll
        for (int k = 0; k < NG; ++k) {
            const float4 e = *(const float4*)&Esh[rh + 8 * k][d4];
            fma4(acc[k], e.x, t0); fma4(acc[k], e.y, t1);
            fma4(acc[k], e.z, t2); fma4(acc[k], e.w, t3);
        }
    }

    #pragma unroll
    for (int k = 0; k < NG; ++k) {
        const int r = rh + 8 * k;
        if (r < my_rows) {
            float* dst = P + (size_t)rows_chunk[r].y * D + col0;
            *(float4*)dst = acc[k];
        }
    }
}

// block (u, half): owns SLOT half of bin u — the triplets with
// idx[b][3+half] == u. Row sets are disjoint-and-covering by construction
// (no cross-block list-order coordination needed; fixes r11 bug). Each block
// scans one idx column, builds its LDS row list, processes ALL its chunks.
// dest = b*4 + ht*2 + half. P[dest] value is order-independent (fixed
// d-ascending FMA chain) -> deterministic output.
__global__ __launch_bounds__(256) void matvec_scan_kernel(
    const int* __restrict__ idx, const float* __restrict__ ent,
    const float* __restrict__ tt, float* __restrict__ P, int B)
{
    const int u    = blockIdx.x;
    const int half = blockIdx.y;           // slot
    const int tid  = threadIdx.x;

    __shared__ int2 s_rows[MAXR];
    __shared__ int  s_m;
    __shared__ float Esh[32][D + 4];       // 16.9 KB
    if (tid == 0) s_m = 0;
    __syncthreads();

    // ---- scan phase: triplets with idx[b][3+half] == u ----
    #pragma unroll 4
    for (int b = tid; b < B; b += 256) {
        if (idx[b * 5 + 3 + half] == u) {
            const int he = idx[b * 5 + 0];
            const int te = idx[b * 5 + 2];
            const int p = atomicAdd(&s_m, 2);
            if (p + 1 < MAXR) {
                s_rows[p]     = make_int2(he, b * 4 + 0 + half);   // h row
                s_rows[p + 1] = make_int2(te, b * 4 + 2 + half);   // t row
            }
        }
    }
    __syncthreads();
    int n_rows = s_m;
    if (n_rows > MAXR) n_rows = MAXR;
    if (n_rows == 0) return;

    const int w    = tid >> 6;             // wave 0..3 -> col slice w*32
    const int lane = tid & 63;
    const int c8   = lane & 7;
    const int rh   = lane >> 3;            // 0..7
    const int col0 = w * 32 + c8 * 4;

    const float* __restrict__ Tc = tt + (size_t)u * (D * D) + col0;

    for (int rr0 = 0; rr0 < n_rows; rr0 += 32) {
        const int my_rows = min(32, n_rows - rr0);

        {   // stage my_rows entity rows: 8 threads/row, 16 floats each
            const int r  = tid >> 3;
            const int j8 = tid & 7;
            if (r < my_rows) {
                const int eid = s_rows[rr0 + r].x;
                const float* src = ent + (size_t)eid * D + j8 * 16;
                const float4 v0 = *(const float4*)(src);
                const float4 v1 = *(const float4*)(src + 4);
                const float4 v2 = *(const float4*)(src + 8);
                const float4 v3 = *(const float4*)(src + 12);
                float* drow = &Esh[r][j8 * 16];
                *(float4*)(drow)      = v0;
                *(float4*)(drow + 4)  = v1;
                *(float4*)(drow + 8)  = v2;
                *(float4*)(drow + 12) = v3;
            }
        }
        __syncthreads();

        const int ng = (my_rows + 7) >> 3;   // 1..4, wave-uniform
        switch (ng) {
            case 1: compute_store<1>(Tc, Esh, &s_rows[rr0], P, col0, rh, my_rows); break;
            case 2: compute_store<2>(Tc, Esh, &s_rows[rr0], P, col0, rh, my_rows); break;
            case 3: compute_store<3>(Tc, Esh, &s_rows[rr0], P, col0, rh, my_rows); break;
            default: compute_store<4>(Tc, Esh, &s_rows[rr0], P, col0, rh, my_rows); break;
        }
        __syncthreads();
    }
}

__global__ __launch_bounds__(256) void score_kernel(
    const int* __restrict__ idx, const float* __restrict__ rel,
    const float* __restrict__ P, float* __restrict__ out, int B)
{
    const int tid = threadIdx.x;
    const int b = blockIdx.x * 4 + (tid >> 6);
    const int l = tid & 63;
    if (b >= B) return;

    const int ri = idx[b * 5 + 1];
    const float* ph = P + (size_t)(b * 4 + 0) * D;   // dests b*4+0, b*4+1
    const float* pt = P + (size_t)(b * 4 + 2) * D;   // dests b*4+2, b*4+3

    const float h0 = ph[l]      + ph[D + l];
    const float h1 = ph[64 + l] + ph[D + 64 + l];
    const float t0 = pt[l]      + pt[D + l];
    const float t1 = pt[64 + l] + pt[D + 64 + l];

    float nh = h0 * h0 + h1 * h1;
    float nt = t0 * t0 + t1 * t1;
    #pragma unroll
    for (int off = 32; off; off >>= 1) {
        nh += __shfl_down(nh, off, 64);
        nt += __shfl_down(nt, off, 64);
    }
    nh = __shfl(nh, 0, 64);
    nt = __shfl(nt, 0, 64);
    const float rnh = 1.0f / fmaxf(sqrtf(nh), 1e-12f);
    const float rnt = 1.0f / fmaxf(sqrtf(nt), 1e-12f);
    const float r0 = rel[(size_t)ri * D + l];
    const float r1 = rel[(size_t)ri * D + 64 + l];
    float v = fabsf(h0 * rnh + r0 - t0 * rnt + 1e-6f)
            + fabsf(h1 * rnh + r1 - t1 * rnt + 1e-6f);
    #pragma unroll
    for (int off = 32; off; off >>= 1) v += __shfl_down(v, off, 64);
    if (l == 0) out[b] = v;
}

extern "C" void kernel_launch(void* const* d_in, const int* in_sizes, int n_in,
                              void* d_out, int out_size, void* d_ws, size_t ws_size,
                              hipStream_t stream) {
    const int*   idx = (const int*)d_in[0];
    const float* ent = (const float*)d_in[1];
    const float* rel = (const float*)d_in[2];
    const float* tt  = (const float*)d_in[3];
    float* out = (float*)d_out;
    const int B  = in_sizes[0] / 5;
    const int NT = in_sizes[3] / (D * D);   // number of time matrices (1000)

    const size_t need = (size_t)B * 4 * D * sizeof(float);   // P only

    if (ws_size < need) {
        transe_time_kernel<<<dim3(B), dim3(256), 0, stream>>>(idx, ent, rel, tt, out, B);
        return;
    }

    float* P = (float*)d_ws;

    matvec_scan_kernel<<<dim3(NT, 2),       dim3(256), 0, stream>>>(idx, ent, tt, P, B);
    score_kernel      <<<dim3((B + 3) / 4), dim3(256), 0, stream>>>(idx, rel, P, out, B);
}

// Round 13
// 54.575 us; speedup vs baseline: 1.1953x; 1.1953x over previous
//
#include <hip/hip_runtime.h>

#define D 128
#define CAP_R 128   // max rows per bin (rows = 2*matches; mean 32.8)

// ---------------- fallback (round-1) kernel ----------------
__global__ __launch_bounds__(256) void transe_time_kernel(
    const int* __restrict__ idx, const float* __restrict__ ent,
    const float* __restrict__ rel, const float* __restrict__ tt,
    float* __restrict__ out, int B)
{
    const int b = blockIdx.x;
    if (b >= B) return;
    const int tid = threadIdx.x;
    const int e4  = tid & 31;
    const int g   = tid >> 5;

    __shared__ float sh_h[D];
    __shared__ float sh_t[D];
    __shared__ float ph[8][D];
    __shared__ float pt[8][D];
    __shared__ float wred[8];

    const int hi = idx[b * 5 + 0];
    const int ri = idx[b * 5 + 1];
    const int ti = idx[b * 5 + 2];
    const int si = idx[b * 5 + 3];
    const int ei = idx[b * 5 + 4];

    if (tid < D) {
        sh_h[tid] = ent[(size_t)hi * D + tid];
        sh_t[tid] = ent[(size_t)ti * D + tid];
    }
    __syncthreads();

    const float4* __restrict__ Ts = (const float4*)(tt + (size_t)si * D * D);
    const float4* __restrict__ Te = (const float4*)(tt + (size_t)ei * D * D);

    float4 hacc = make_float4(0.f, 0.f, 0.f, 0.f);
    float4 tacc = make_float4(0.f, 0.f, 0.f, 0.f);

    #pragma unroll 4
    for (int d0 = 0; d0 < D; d0 += 8) {
        const int d = d0 + g;
        const float4 a = Ts[d * 32 + e4];
        const float4 c = Te[d * 32 + e4];
        const float hd = sh_h[d];
        const float td = sh_t[d];
        const float mx = a.x + c.x;
        const float my = a.y + c.y;
        const float mz = a.z + c.z;
        const float mw = a.w + c.w;
        hacc.x += hd * mx; hacc.y += hd * my; hacc.z += hd * mz; hacc.w += hd * mw;
        tacc.x += td * mx; tacc.y += td * my; tacc.z += td * mz; tacc.w += td * mw;
    }

    ((float4*)ph[g])[e4] = hacc;
    ((float4*)pt[g])[e4] = tacc;
    __syncthreads();

    float h2 = 0.f, t2 = 0.f;
    if (tid < D) {
        #pragma unroll
        for (int k = 0; k < 8; ++k) { h2 += ph[k][tid]; t2 += pt[k][tid]; }
    }
    float nh = h2 * h2;
    float nt = t2 * t2;
    #pragma unroll
    for (int off = 32; off; off >>= 1) {
        nh += __shfl_down(nh, off, 64);
        nt += __shfl_down(nt, off, 64);
    }
    const int wv = tid >> 6;
    if ((tid & 63) == 0) { wred[wv * 2] = nh; wred[wv * 2 + 1] = nt; }
    __syncthreads();
    const float NH = wred[0] + wred[2] + wred[4] + wred[6];
    const float NT2 = wred[1] + wred[3] + wred[5] + wred[7];
    const float rnh = 1.0f / fmaxf(sqrtf(NH), 1e-12f);
    const float rnt = 1.0f / fmaxf(sqrtf(NT2), 1e-12f);

    float v = 0.f;
    if (tid < D) {
        const float rr = rel[(size_t)ri * D + tid];
        v = fabsf(h2 * rnh + rr - t2 * rnt + 1e-6f);
    }
    #pragma unroll
    for (int off = 32; off; off >>= 1) v += __shfl_down(v, off, 64);
    __syncthreads();
    if ((tid & 63) == 0) wred[wv] = v;
    __syncthreads();
    if (tid == 0) out[b] = wred[0] + wred[1] + wred[2] + wred[3];
}

// ---------------- binned pipeline: zero -> scatter -> matvec -> score -------

__global__ __launch_bounds__(1024) void zero_cnt_kernel(int* __restrict__ cnt, int NT)
{
    const int t = threadIdx.x;
    if (t < NT) cnt[t] = 0;
}

// emits self-contained row records: rows[u*CAP_R + p] = {eid, dest}
// dest = (b*2 + ht)*2 + slot ; row pair (h,t) appended together.
__global__ __launch_bounds__(256) void scatter_kernel(
    const int* __restrict__ idx, int* __restrict__ cnt,
    int2* __restrict__ rowsbuf, int B)
{
    const int i = blockIdx.x * blockDim.x + threadIdx.x;
    const int stride = gridDim.x * blockDim.x;
    for (int b = i; b < B; b += stride) {
        const int h_eid = idx[b * 5 + 0];
        const int t_eid = idx[b * 5 + 2];
        #pragma unroll
        for (int slot = 0; slot < 2; ++slot) {
            const int u = idx[b * 5 + 3 + slot];
            const int p = atomicAdd(&cnt[u], 2);
            if (p + 1 < CAP_R) {
                rowsbuf[u * CAP_R + p]     = make_int2(h_eid, (b * 2 + 0) * 2 + slot);
                rowsbuf[u * CAP_R + p + 1] = make_int2(t_eid, (b * 2 + 1) * 2 + slot);
            }
        }
    }
}

__device__ __forceinline__ void fma4(float4& a, float s, const float4& v) {
    a.x += s * v.x; a.y += s * v.y; a.z += s * v.z; a.w += s * v.w;
}

// NG = number of live 8-row groups (wave-uniform).
template<int NG>
__device__ __forceinline__ void compute_store(
    const float* __restrict__ Tc, const float (*__restrict__ Esh)[D + 4],
    const int* __restrict__ Dsh, float* __restrict__ P,
    const int col0, const int rh, const int my_rows)
{
    float4 acc[NG];
    #pragma unroll
    for (int k = 0; k < NG; ++k) acc[k] = make_float4(0.f, 0.f, 0.f, 0.f);

    #pragma unroll 2
    for (int d4 = 0; d4 < D; d4 += 4) {
        const float* tp = Tc + (size_t)d4 * D;
        const float4 t0 = *(const float4*)(tp);
        const float4 t1 = *(const float4*)(tp + D);
        const float4 t2 = *(const float4*)(tp + 2 * D);
        const float4 t3 = *(const float4*)(tp + 3 * D);
        #pragma unroll
        for (int k = 0; k < NG; ++k) {
            const float4 e = *(const float4*)&Esh[rh + 8 * k][d4];
            fma4(acc[k], e.x, t0); fma4(acc[k], e.y, t1);
            fma4(acc[k], e.z, t2); fma4(acc[k], e.w, t3);
        }
    }

    #pragma unroll
    for (int k = 0; k < NG; ++k) {
        const int r = rh + 8 * k;
        if (r < my_rows) {
            float* dst = P + (size_t)Dsh[r] * D + col0;
            *(float4*)dst = acc[k];
        }
    }
}

// block (u, half): takes rows half, half+2, half+4, ... of bin u (parity
// split: disjoint, covering, BALANCED ~16.4 rows each — fixes r10's
// imbalance where half 1 got rows-32 ≈ 0). Both halves stream the same T;
// linear block ids u and u+NT land on the same XCD (NT % 8 == 0) -> L2 share.
__global__ __launch_bounds__(256) void matvec_kernel(
    const float* __restrict__ ent, const float* __restrict__ tt,
    const int* __restrict__ cnt, const int2* __restrict__ rowsbuf,
    float* __restrict__ P)
{
    const int u = blockIdx.x;
    const int half = blockIdx.y;
    int n_rows = cnt[u];
    if (n_rows > CAP_R) n_rows = CAP_R;
    // my rows: rr = half + 2*k, k = 0..my_total-1
    const int my_total = (n_rows > half) ? ((n_rows - half + 1) >> 1) : 0;
    if (my_total == 0) return;
    const int base = u * CAP_R;
    const int tid = threadIdx.x;

    const int w    = tid >> 6;             // wave 0..3 -> col slice w*32
    const int lane = tid & 63;
    const int c8   = lane & 7;
    const int rh   = lane >> 3;            // 0..7
    const int col0 = w * 32 + c8 * 4;

    __shared__ float Esh[32][D + 4];       // 16.9 KB
    __shared__ int   Dsh[32];
    const float* __restrict__ Tc = tt + (size_t)u * (D * D) + col0;

    for (int k0 = 0; k0 < my_total; k0 += 32) {
        const int my_rows = min(32, my_total - k0);

        {   // stage my_rows entity rows: 8 threads/row, 16 floats each
            const int r  = tid >> 3;       // local row 0..31
            const int j8 = tid & 7;
            if (r < my_rows) {
                const int2 rec = rowsbuf[base + half + 2 * (k0 + r)];
                const float* src = ent + (size_t)rec.x * D + j8 * 16;
                const float4 v0 = *(const float4*)(src);
                const float4 v1 = *(const float4*)(src + 4);
                const float4 v2 = *(const float4*)(src + 8);
                const float4 v3 = *(const float4*)(src + 12);
                float* drow = &Esh[r][j8 * 16];
                *(float4*)(drow)      = v0;
                *(float4*)(drow + 4)  = v1;
                *(float4*)(drow + 8)  = v2;
                *(float4*)(drow + 12) = v3;
                if (j8 == 0) Dsh[r] = rec.y;
            }
        }
        __syncthreads();

        const int ng = (my_rows + 7) >> 3;   // 1..4, wave-uniform
        switch (ng) {
            case 1: compute_store<1>(Tc, Esh, Dsh, P, col0, rh, my_rows); break;
            case 2: compute_store<2>(Tc, Esh, Dsh, P, col0, rh, my_rows); break;
            case 3: compute_store<3>(Tc, Esh, Dsh, P, col0, rh, my_rows); break;
            default: compute_store<4>(Tc, Esh, Dsh, P, col0, rh, my_rows); break;
        }
        __syncthreads();
    }
}

__global__ __launch_bounds__(256) void score_kernel(
    const int* __restrict__ idx, const float* __restrict__ rel,
    const float* __restrict__ P, float* __restrict__ out, int B)
{
    const int tid = threadIdx.x;
    const int b = blockIdx.x * 4 + (tid >> 6);
    const int l = tid & 63;
    if (b >= B) return;

    const int ri = idx[b * 5 + 1];
    const float* ph = P + (size_t)(b * 2 + 0) * 2 * D;
    const float* pt = P + (size_t)(b * 2 + 1) * 2 * D;

    const float h0 = ph[l]      + ph[D + l];
    const float h1 = ph[64 + l] + ph[D + 64 + l];
    const float t0 = pt[l]      + pt[D + l];
    const float t1 = pt[64 + l] + pt[D + 64 + l];

    float nh = h0 * h0 + h1 * h1;
    float nt = t0 * t0 + t1 * t1;
    #pragma unroll
    for (int off = 32; off; off >>= 1) {
        nh += __shfl_down(nh, off, 64);
        nt += __shfl_down(nt, off, 64);
    }
    nh = __shfl(nh, 0, 64);
    nt = __shfl(nt, 0, 64);
    const float rnh = 1.0f / fmaxf(sqrtf(nh), 1e-12f);
    const float rnt = 1.0f / fmaxf(sqrtf(nt), 1e-12f);
    const float r0 = rel[(size_t)ri * D + l];
    const float r1 = rel[(size_t)ri * D + 64 + l];
    float v = fabsf(h0 * rnh + r0 - t0 * rnt + 1e-6f)
            + fabsf(h1 * rnh + r1 - t1 * rnt + 1e-6f);
    #pragma unroll
    for (int off = 32; off; off >>= 1) v += __shfl_down(v, off, 64);
    if (l == 0) out[b] = v;
}

extern "C" void kernel_launch(void* const* d_in, const int* in_sizes, int n_in,
                              void* d_out, int out_size, void* d_ws, size_t ws_size,
                              hipStream_t stream) {
    const int*   idx = (const int*)d_in[0];
    const float* ent = (const float*)d_in[1];
    const float* rel = (const float*)d_in[2];
    const float* tt  = (const float*)d_in[3];
    float* out = (float*)d_out;
    const int B  = in_sizes[0] / 5;
    const int NT = in_sizes[3] / (D * D);   // number of time matrices (1000)

    const size_t CNT_OFF  = 0;
    const size_t ROWS_OFF = 8192;
    const size_t ROWS_BYTES = (size_t)NT * CAP_R * sizeof(int2);
    const size_t P_OFF  = (ROWS_OFF + ROWS_BYTES + 255) & ~(size_t)255;
    const size_t need   = P_OFF + (size_t)B * 2 * 2 * D * sizeof(float);

    if (ws_size < need || NT > 1024) {
        transe_time_kernel<<<dim3(B), dim3(256), 0, stream>>>(idx, ent, rel, tt, out, B);
        return;
    }

    char* ws = (char*)d_ws;
    int*  cnt     = (int*)(ws + CNT_OFF);
    int2* rowsbuf = (int2*)(ws + ROWS_OFF);
    float* P      = (float*)(ws + P_OFF);

    zero_cnt_kernel<<<dim3(1),           dim3(1024), 0, stream>>>(cnt, NT);
    scatter_kernel <<<dim3(32),          dim3(256),  0, stream>>>(idx, cnt, rowsbuf, B);
    matvec_kernel  <<<dim3(NT, 2),       dim3(256),  0, stream>>>(ent, tt, cnt, rowsbuf, P);
    score_kernel   <<<dim3((B + 3) / 4), dim3(256),  0, stream>>>(idx, rel, P, out, B);
}

// Round 14
// 50.223 us; speedup vs baseline: 1.2988x; 1.0867x over previous
//
#include <hip/hip_runtime.h>

#define D 128
#define CAP_R 128   // max rows per bin (rows = 2*matches; mean 32.8)

// ---------------- fallback (round-1) kernel ----------------
__global__ __launch_bounds__(256) void transe_time_kernel(
    const int* __restrict__ idx, const float* __restrict__ ent,
    const float* __restrict__ rel, const float* __restrict__ tt,
    float* __restrict__ out, int B)
{
    const int b = blockIdx.x;
    if (b >= B) return;
    const int tid = threadIdx.x;
    const int e4  = tid & 31;
    const int g   = tid >> 5;

    __shared__ float sh_h[D];
    __shared__ float sh_t[D];
    __shared__ float ph[8][D];
    __shared__ float pt[8][D];
    __shared__ float wred[8];

    const int hi = idx[b * 5 + 0];
    const int ri = idx[b * 5 + 1];
    const int ti = idx[b * 5 + 2];
    const int si = idx[b * 5 + 3];
    const int ei = idx[b * 5 + 4];

    if (tid < D) {
        sh_h[tid] = ent[(size_t)hi * D + tid];
        sh_t[tid] = ent[(size_t)ti * D + tid];
    }
    __syncthreads();

    const float4* __restrict__ Ts = (const float4*)(tt + (size_t)si * D * D);
    const float4* __restrict__ Te = (const float4*)(tt + (size_t)ei * D * D);

    float4 hacc = make_float4(0.f, 0.f, 0.f, 0.f);
    float4 tacc = make_float4(0.f, 0.f, 0.f, 0.f);

    #pragma unroll 4
    for (int d0 = 0; d0 < D; d0 += 8) {
        const int d = d0 + g;
        const float4 a = Ts[d * 32 + e4];
        const float4 c = Te[d * 32 + e4];
        const float hd = sh_h[d];
        const float td = sh_t[d];
        const float mx = a.x + c.x;
        const float my = a.y + c.y;
        const float mz = a.z + c.z;
        const float mw = a.w + c.w;
        hacc.x += hd * mx; hacc.y += hd * my; hacc.z += hd * mz; hacc.w += hd * mw;
        tacc.x += td * mx; tacc.y += td * my; tacc.z += td * mz; tacc.w += td * mw;
    }

    ((float4*)ph[g])[e4] = hacc;
    ((float4*)pt[g])[e4] = tacc;
    __syncthreads();

    float h2 = 0.f, t2 = 0.f;
    if (tid < D) {
        #pragma unroll
        for (int k = 0; k < 8; ++k) { h2 += ph[k][tid]; t2 += pt[k][tid]; }
    }
    float nh = h2 * h2;
    float nt = t2 * t2;
    #pragma unroll
    for (int off = 32; off; off >>= 1) {
        nh += __shfl_down(nh, off, 64);
        nt += __shfl_down(nt, off, 64);
    }
    const int wv = tid >> 6;
    if ((tid & 63) == 0) { wred[wv * 2] = nh; wred[wv * 2 + 1] = nt; }
    __syncthreads();
    const float NH = wred[0] + wred[2] + wred[4] + wred[6];
    const float NT2 = wred[1] + wred[3] + wred[5] + wred[7];
    const float rnh = 1.0f / fmaxf(sqrtf(NH), 1e-12f);
    const float rnt = 1.0f / fmaxf(sqrtf(NT2), 1e-12f);

    float v = 0.f;
    if (tid < D) {
        const float rr = rel[(size_t)ri * D + tid];
        v = fabsf(h2 * rnh + rr - t2 * rnt + 1e-6f);
    }
    #pragma unroll
    for (int off = 32; off; off >>= 1) v += __shfl_down(v, off, 64);
    __syncthreads();
    if ((tid & 63) == 0) wred[wv] = v;
    __syncthreads();
    if (tid == 0) out[b] = wred[0] + wred[1] + wred[2] + wred[3];
}

// ---------------- binned pipeline: zero -> scatter -> matvec -> score -------

__global__ __launch_bounds__(1024) void zero_cnt_kernel(int* __restrict__ cnt, int NT)
{
    const int t = threadIdx.x;
    if (t < NT) cnt[t] = 0;
}

// emits self-contained row records: rows[u*CAP_R + p] = {eid, y}
// y = b*4 + ht*2 + slot ; row pair (h,t) appended together.
__global__ __launch_bounds__(256) void scatter_kernel(
    const int* __restrict__ idx, int* __restrict__ cnt,
    int2* __restrict__ rowsbuf, int B)
{
    const int i = blockIdx.x * blockDim.x + threadIdx.x;
    const int stride = gridDim.x * blockDim.x;
    for (int b = i; b < B; b += stride) {
        const int h_eid = idx[b * 5 + 0];
        const int t_eid = idx[b * 5 + 2];
        #pragma unroll
        for (int slot = 0; slot < 2; ++slot) {
            const int u = idx[b * 5 + 3 + slot];
            const int p = atomicAdd(&cnt[u], 2);
            if (p + 1 < CAP_R) {
                rowsbuf[u * CAP_R + p]     = make_int2(h_eid, b * 4 + 0 + slot);
                rowsbuf[u * CAP_R + p + 1] = make_int2(t_eid, b * 4 + 2 + slot);
            }
        }
    }
}

__device__ __forceinline__ void fma4(float4& a, float s, const float4& v) {
    a.x += s * v.x; a.y += s * v.y; a.z += s * v.z; a.w += s * v.w;
}

// NG = number of live 8-row groups (wave-uniform). 64-wide d-half contraction.
template<int NG>
__device__ __forceinline__ void compute_store(
    const float* __restrict__ Tc, const float (*__restrict__ Esh)[68],
    const int* __restrict__ Dsh, float* __restrict__ P,
    const int col0, const int rh, const int my_rows, const int dh)
{
    float4 acc[NG];
    #pragma unroll
    for (int k = 0; k < NG; ++k) acc[k] = make_float4(0.f, 0.f, 0.f, 0.f);

    #pragma unroll 2
    for (int d4 = 0; d4 < 64; d4 += 4) {
        const float* tp = Tc + (size_t)d4 * D;
        const float4 t0 = *(const float4*)(tp);
        const float4 t1 = *(const float4*)(tp + D);
        const float4 t2 = *(const float4*)(tp + 2 * D);
        const float4 t3 = *(const float4*)(tp + 3 * D);
        #pragma unroll
        for (int k = 0; k < NG; ++k) {
            const float4 e = *(const float4*)&Esh[rh + 8 * k][d4];
            fma4(acc[k], e.x, t0); fma4(acc[k], e.y, t1);
            fma4(acc[k], e.z, t2); fma4(acc[k], e.w, t3);
        }
    }

    #pragma unroll
    for (int k = 0; k < NG; ++k) {
        const int r = rh + 8 * k;
        if (r < my_rows) {
            float* dst = P + (size_t)((Dsh[r] << 1) | dh) * D + col0;
            *(float4*)dst = acc[k];
        }
    }
}

// block (u, dh): contraction-half dh of ALL rows of bin u.
//  - T rows [dh*64, dh*64+64): disjoint 32KB per block -> T traffic = 64MB total
//  - stages only the d-half of each entity row (64 floats): staging disjoint
//  - perfectly balanced across the 2 blocks of a bin
//  - chunk=64 rows -> single chunk for ~100% of bins (mean 32.8 rows)
// P slot = rec.y*2 + dh, written exactly once -> deterministic.
__global__ __launch_bounds__(256) void matvec_kernel(
    const float* __restrict__ ent, const float* __restrict__ tt,
    const int* __restrict__ cnt, const int2* __restrict__ rowsbuf,
    float* __restrict__ P)
{
    const int u  = blockIdx.x;
    const int dh = blockIdx.y;
    int n_rows = cnt[u];
    if (n_rows == 0) return;
    if (n_rows > CAP_R) n_rows = CAP_R;
    const int base = u * CAP_R;
    const int tid = threadIdx.x;

    const int w    = tid >> 6;             // wave 0..3 -> col slice w*32
    const int lane = tid & 63;
    const int c8   = lane & 7;
    const int rh   = lane >> 3;            // 0..7
    const int col0 = w * 32 + c8 * 4;

    __shared__ float Esh[64][68];          // 17.4 KB (pad 4: conflict-free)
    __shared__ int   Dsh[64];
    const float* __restrict__ Tc = tt + (size_t)u * (D * D) + (size_t)dh * 64 * D + col0;

    for (int rr0 = 0; rr0 < n_rows; rr0 += 64) {
        const int my_rows = min(64, n_rows - rr0);

        {   // stage d-half of my_rows entity rows: 4 threads/row, 16 floats each
            const int r = tid >> 2;        // 0..63
            const int q = tid & 3;         // floats q*16 .. +15
            if (r < my_rows) {
                const int2 rec = rowsbuf[base + rr0 + r];
                const float* src = ent + (size_t)rec.x * D + dh * 64 + q * 16;
                const float4 v0 = *(const float4*)(src);
                const float4 v1 = *(const float4*)(src + 4);
                const float4 v2 = *(const float4*)(src + 8);
                const float4 v3 = *(const float4*)(src + 12);
                float* drow = &Esh[r][q * 16];
                *(float4*)(drow)      = v0;
                *(float4*)(drow + 4)  = v1;
                *(float4*)(drow + 8)  = v2;
                *(float4*)(drow + 12) = v3;
                if (q == 0) Dsh[r] = rec.y;
            }
        }
        __syncthreads();

        const int ng = (my_rows + 7) >> 3;   // 1..8, wave-uniform
        switch (ng) {
            case 1: compute_store<1>(Tc, Esh, Dsh, P, col0, rh, my_rows, dh); break;
            case 2: compute_store<2>(Tc, Esh, Dsh, P, col0, rh, my_rows, dh); break;
            case 3: compute_store<3>(Tc, Esh, Dsh, P, col0, rh, my_rows, dh); break;
            case 4: compute_store<4>(Tc, Esh, Dsh, P, col0, rh, my_rows, dh); break;
            case 5: compute_store<5>(Tc, Esh, Dsh, P, col0, rh, my_rows, dh); break;
            case 6: compute_store<6>(Tc, Esh, Dsh, P, col0, rh, my_rows, dh); break;
            case 7: compute_store<7>(Tc, Esh, Dsh, P, col0, rh, my_rows, dh); break;
            default: compute_store<8>(Tc, Esh, Dsh, P, col0, rh, my_rows, dh); break;
        }
        __syncthreads();
    }
}

// P rows per triplet b: b*8 + ht*4 + slot*2 + dh ; h = rows b*8+0..3, t = +4..7
__global__ __launch_bounds__(256) void score_kernel(
    const int* __restrict__ idx, const float* __restrict__ rel,
    const float* __restrict__ P, float* __restrict__ out, int B)
{
    const int tid = threadIdx.x;
    const int b = blockIdx.x * 4 + (tid >> 6);
    const int l = tid & 63;
    if (b >= B) return;

    const int ri = idx[b * 5 + 1];
    const float* pb = P + (size_t)b * 8 * D;

    float h0 = 0.f, h1 = 0.f, t0 = 0.f, t1 = 0.f;
    #pragma unroll
    for (int j = 0; j < 4; ++j) {
        h0 += pb[j * D + l];
        h1 += pb[j * D + 64 + l];
        t0 += pb[(4 + j) * D + l];
        t1 += pb[(4 + j) * D + 64 + l];
    }

    float nh = h0 * h0 + h1 * h1;
    float nt = t0 * t0 + t1 * t1;
    #pragma unroll
    for (int off = 32; off; off >>= 1) {
        nh += __shfl_down(nh, off, 64);
        nt += __shfl_down(nt, off, 64);
    }
    nh = __shfl(nh, 0, 64);
    nt = __shfl(nt, 0, 64);
    const float rnh = 1.0f / fmaxf(sqrtf(nh), 1e-12f);
    const float rnt = 1.0f / fmaxf(sqrtf(nt), 1e-12f);
    const float r0 = rel[(size_t)ri * D + l];
    const float r1 = rel[(size_t)ri * D + 64 + l];
    float v = fabsf(h0 * rnh + r0 - t0 * rnt + 1e-6f)
            + fabsf(h1 * rnh + r1 - t1 * rnt + 1e-6f);
    #pragma unroll
    for (int off = 32; off; off >>= 1) v += __shfl_down(v, off, 64);
    if (l == 0) out[b] = v;
}

extern "C" void kernel_launch(void* const* d_in, const int* in_sizes, int n_in,
                              void* d_out, int out_size, void* d_ws, size_t ws_size,
                              hipStream_t stream) {
    const int*   idx = (const int*)d_in[0];
    const float* ent = (const float*)d_in[1];
    const float* rel = (const float*)d_in[2];
    const float* tt  = (const float*)d_in[3];
    float* out = (float*)d_out;
    const int B  = in_sizes[0] / 5;
    const int NT = in_sizes[3] / (D * D);   // number of time matrices (1000)

    const size_t CNT_OFF  = 0;
    const size_t ROWS_OFF = 8192;
    const size_t ROWS_BYTES = (size_t)NT * CAP_R * sizeof(int2);
    const size_t P_OFF  = (ROWS_OFF + ROWS_BYTES + 255) & ~(size_t)255;
    const size_t need   = P_OFF + (size_t)B * 8 * D * sizeof(float);

    if (ws_size < need || NT > 1024) {
        transe_time_kernel<<<dim3(B), dim3(256), 0, stream>>>(idx, ent, rel, tt, out, B);
        return;
    }

    char* ws = (char*)d_ws;
    int*  cnt     = (int*)(ws + CNT_OFF);
    int2* rowsbuf = (int2*)(ws + ROWS_OFF);
    float* P      = (float*)(ws + P_OFF);

    zero_cnt_kernel<<<dim3(1),           dim3(1024), 0, stream>>>(cnt, NT);
    scatter_kernel <<<dim3(32),          dim3(256),  0, stream>>>(idx, cnt, rowsbuf, B);
    matvec_kernel  <<<dim3(NT, 2),       dim3(256),  0, stream>>>(ent, tt, cnt, rowsbuf, P);
    score_kernel   <<<dim3((B + 3) / 4), dim3(256),  0, stream>>>(idx, rel, P, out, B);
}